// Round 1
// baseline (473.569 us; speedup 1.0000x reference)
//
#include <hip/hip_runtime.h>
#include <hip/hip_bf16.h>

// Problem: per-sample dynamic conv.
// x:[16,64,128,128] f32; w1:[128,32]; b1:[32]; w2:[32,36864]; b2:[36864]
// stats -> h=relu(stats@w1+b1) -> kern[b,64,64,3,3]=h@w2+b2 -> conv(pad=1)
// out:[16,64,128,128] f32

#define B_ 16
#define CI_ 64
#define CO_ 64
#define HW_ 128
#define NPIX 16384          // 128*128
#define KELEM 36864         // 64*64*9

// ---------------- Kernel A: per-(b,ci) mean/std (ddof=1) ----------------
__global__ void stats_kernel(const float* __restrict__ x, float* __restrict__ stats) {
    int bc = blockIdx.x;                 // b*64+ci
    const float4* p4 = (const float4*)(x + (size_t)bc * NPIX);
    float s = 0.f, ss = 0.f;
    for (int i = threadIdx.x; i < NPIX / 4; i += 256) {
        float4 v = p4[i];
        s  += v.x + v.y + v.z + v.w;
        ss += v.x * v.x + v.y * v.y + v.z * v.z + v.w * v.w;
    }
    for (int off = 32; off; off >>= 1) {
        s  += __shfl_down(s, off);
        ss += __shfl_down(ss, off);
    }
    __shared__ float sm[8];
    int wid = threadIdx.x >> 6, lane = threadIdx.x & 63;
    if (lane == 0) { sm[wid] = s; sm[4 + wid] = ss; }
    __syncthreads();
    if (threadIdx.x == 0) {
        s  = sm[0] + sm[1] + sm[2] + sm[3];
        ss = sm[4] + sm[5] + sm[6] + sm[7];
        float mean = s * (1.f / NPIX);
        float var  = fmaxf((ss - s * mean) * (1.f / (NPIX - 1)), 0.f);
        int b = bc >> 6, ci = bc & 63;
        stats[b * 128 + ci]      = mean;
        stats[b * 128 + 64 + ci] = sqrtf(var);
    }
}

// ---------------- Kernel B: h = relu(stats@w1+b1); kern = h@w2+b2 ----------------
__global__ void kern_gen(const float* __restrict__ stats,
                         const float* __restrict__ w1, const float* __restrict__ b1,
                         const float* __restrict__ w2, const float* __restrict__ b2,
                         float* __restrict__ kern) {
    int b = blockIdx.x, chunk = blockIdx.y;   // chunk: 0..8, 4096 j's each
    __shared__ float st[128];
    __shared__ float h[32];
    int t = threadIdx.x;
    if (t < 128) st[t] = stats[b * 128 + t];
    __syncthreads();
    if (t < 32) {
        float acc = b1[t];
        for (int i = 0; i < 128; i++) acc += st[i] * w1[i * 32 + t];
        h[t] = fmaxf(acc, 0.f);
    }
    __syncthreads();
    int j0 = chunk * 4096;
    for (int j = j0 + t; j < j0 + 4096; j += 256) {
        float acc = b2[j];
        #pragma unroll
        for (int i = 0; i < 32; i++) acc += h[i] * w2[i * KELEM + j];
        kern[(size_t)b * KELEM + j] = acc;
    }
}

// ---------------- Kernel C: direct conv, fp32 ----------------
// tile: 16 co x 32x32 pixels per block; thread = 4 co x 4x4 pixels.
// ci staged in chunks of 8 into LDS; weights for (16co x 8ci x 9) in LDS.
__global__ __launch_bounds__(256, 1) void conv_kernel(const float* __restrict__ x,
                                                      const float* __restrict__ kern,
                                                      float* __restrict__ out) {
    __shared__ float xs[8][34][36];      // [ci][y][x], row padded to 36 (16B-aligned rows)
    __shared__ float wsm[16][8][12];     // [co][ci][k], padded to 12 (16B-aligned rows)

    int tile = blockIdx.x;               // 0..15 (4x4 spatial tiles of 32x32)
    int cog  = blockIdx.y;               // 0..3  (co groups of 16)
    int b    = blockIdx.z;               // 0..15
    int gy0 = (tile >> 2) * 32, gx0 = (tile & 3) * 32;

    int t    = threadIdx.x;
    int csub = t >> 6;                   // 0..3 -> co_local base csub*4 (wave-uniform)
    int pg   = t & 63;
    int py   = (pg >> 3) * 4;            // 0..28 step 4
    int px   = (pg & 7) * 4;             // 0..28 step 4

    float acc[4][4][4];                  // [co][dy][dx]
    #pragma unroll
    for (int a = 0; a < 4; a++)
        #pragma unroll
        for (int y = 0; y < 4; y++)
            #pragma unroll
            for (int z = 0; z < 4; z++) acc[a][y][z] = 0.f;

    const float* xb = x + (size_t)b * CI_ * NPIX;
    const float* kb = kern + (size_t)b * KELEM + (size_t)cog * 16 * 576; // + co_l*576 + ci*9 + k

    for (int cc = 0; cc < 8; cc++) {
        int ci0 = cc * 8;
        __syncthreads();
        // ---- stage input tile (8 ci x 34 x 34, zero-padded halo) ----
        for (int e = t; e < 8 * 34 * 34; e += 256) {
            int ci  = e / 1156;
            int rem = e - ci * 1156;
            int ly  = rem / 34;
            int lx  = rem - ly * 34;
            int gy = gy0 + ly - 1, gx = gx0 + lx - 1;
            float v = 0.f;
            if ((unsigned)gy < 128u && (unsigned)gx < 128u)
                v = xb[(size_t)(ci0 + ci) * NPIX + gy * 128 + gx];
            xs[ci][ly][lx] = v;
        }
        // ---- stage weights (16 co x 8 ci x 9) ----
        for (int e = t; e < 1152; e += 256) {
            int co = e / 72;
            int r  = e - co * 72;
            int ci = r / 9;
            int k  = r - ci * 9;
            wsm[co][ci][k] = kb[co * 576 + (ci0 + ci) * 9 + k];
        }
        __syncthreads();
        // ---- compute ----
        for (int ci = 0; ci < 8; ci++) {
            float w[4][9];
            #pragma unroll
            for (int co = 0; co < 4; co++)
                #pragma unroll
                for (int k = 0; k < 9; k++) w[co][k] = wsm[csub * 4 + co][ci][k];
            #pragma unroll
            for (int ry = 0; ry < 6; ry++) {
                float row[6];
                #pragma unroll
                for (int j = 0; j < 6; j++) row[j] = xs[ci][py + ry][px + j];
                #pragma unroll
                for (int kh = 0; kh < 3; kh++) {
                    int dy = ry - kh;
                    if (dy >= 0 && dy < 4) {
                        #pragma unroll
                        for (int co = 0; co < 4; co++)
                            #pragma unroll
                            for (int kw = 0; kw < 3; kw++)
                                #pragma unroll
                                for (int dx = 0; dx < 4; dx++)
                                    acc[co][dy][dx] += w[co][kh * 3 + kw] * row[kw + dx];
                    }
                }
            }
        }
    }

    // ---- store 4 co x 4x4 pixels as float4 rows ----
    float* ob = out + ((size_t)(b * CO_ + cog * 16 + csub * 4)) * NPIX;
    #pragma unroll
    for (int co = 0; co < 4; co++)
        #pragma unroll
        for (int dy = 0; dy < 4; dy++) {
            float4 v = make_float4(acc[co][dy][0], acc[co][dy][1],
                                   acc[co][dy][2], acc[co][dy][3]);
            *(float4*)&ob[(size_t)co * NPIX + (gy0 + py + dy) * 128 + gx0 + px] = v;
        }
}

extern "C" void kernel_launch(void* const* d_in, const int* in_sizes, int n_in,
                              void* d_out, int out_size, void* d_ws, size_t ws_size,
                              hipStream_t stream) {
    const float* x  = (const float*)d_in[0];
    const float* w1 = (const float*)d_in[1];
    const float* b1 = (const float*)d_in[2];
    const float* w2 = (const float*)d_in[3];
    const float* b2 = (const float*)d_in[4];
    float* out = (float*)d_out;

    float* ws_stats = (float*)d_ws;                  // 16*128 floats
    float* ws_kern  = ws_stats + B_ * 128;           // 16*36864 floats

    stats_kernel<<<dim3(B_ * CI_), dim3(256), 0, stream>>>(x, ws_stats);
    kern_gen<<<dim3(B_, 9), dim3(256), 0, stream>>>(ws_stats, w1, b1, w2, b2, ws_kern);
    conv_kernel<<<dim3(16, 4, B_), dim3(256), 0, stream>>>(x, ws_kern, out);
}

// Round 2
// 83.671 us; speedup vs baseline: 5.6599x; 5.6599x over previous
//
#include <hip/hip_runtime.h>
#include <hip/hip_bf16.h>

// x:[16,64,128,128] f32 -> stats -> MLP -> per-sample kern[64,64,3,3] -> conv(pad=1)
// Strategy: bf16 MFMA implicit GEMM. xT[b][y][x][ci] bf16 (transposed), weights
// wT[b][co][tap][ci] bf16. Conv = 9 shifted 64x64 GEMMs via mfma_f32_16x16x32_bf16.

#define B_ 16
#define CI_ 64
#define CO_ 64
#define HW_ 128
#define NPIX 16384
#define KEL 36864

typedef __attribute__((ext_vector_type(4))) float f32x4;
typedef __attribute__((ext_vector_type(8))) short short8;

static __device__ __forceinline__ short bf16_of(float f) {
    __hip_bfloat16 h = __float2bfloat16(f);
    return *reinterpret_cast<short*>(&h);
}

// ---------- Kernel 1: transpose x -> xT (bf16, [b][y][x][ci]) + per-(b,ci) stats ----------
// grid (b=16, cig=8); block covers full image for 8 ci -> exact stats, no atomics.
// blockIdx linear = b + 16*cig -> XCD = b%8: all cig-blocks of one b share an XCD L2,
// so the 16B-strided xT writes merge into full lines before HBM writeback.
__global__ __launch_bounds__(256) void xpose_stats(const float* __restrict__ x,
                                                   short* __restrict__ xT,
                                                   float* __restrict__ stats) {
    int b = blockIdx.x, cig = blockIdx.y;
    int t = threadIdx.x;
    float s[8], ss[8];
    #pragma unroll
    for (int c = 0; c < 8; c++) { s[c] = 0.f; ss[c] = 0.f; }
    const float* xb = x + ((size_t)(b * 64 + cig * 8)) * NPIX;
    short* xTb = xT + ((size_t)b * NPIX) * 64 + cig * 8;

    for (int it = 0; it < 16; it++) {
        int pos = it * 256 + t;            // 0..4095 = (y, x/4)
        int y = pos >> 5, x0 = (pos & 31) * 4;
        f32x4 v[8];
        #pragma unroll
        for (int c = 0; c < 8; c++) {
            v[c] = *(const f32x4*)(xb + (size_t)c * NPIX + y * 128 + x0);
            s[c]  += v[c][0] + v[c][1] + v[c][2] + v[c][3];
            ss[c] += v[c][0]*v[c][0] + v[c][1]*v[c][1] + v[c][2]*v[c][2] + v[c][3]*v[c][3];
        }
        #pragma unroll
        for (int xi = 0; xi < 4; xi++) {
            short8 o;
            #pragma unroll
            for (int c = 0; c < 8; c++) o[c] = bf16_of(v[c][xi]);
            *(short8*)(xTb + ((size_t)(y * 128 + x0 + xi)) * 64) = o;
        }
    }

    __shared__ float red[4][16];
    int lane = t & 63, w = t >> 6;
    #pragma unroll
    for (int c = 0; c < 8; c++) {
        float a = s[c], q = ss[c];
        for (int off = 32; off; off >>= 1) { a += __shfl_down(a, off); q += __shfl_down(q, off); }
        if (lane == 0) { red[w][c * 2] = a; red[w][c * 2 + 1] = q; }
    }
    __syncthreads();
    if (t < 8) {
        float a = red[0][t*2] + red[1][t*2] + red[2][t*2] + red[3][t*2];
        float q = red[0][t*2+1] + red[1][t*2+1] + red[2][t*2+1] + red[3][t*2+1];
        float mean = a * (1.f / NPIX);
        float var = fmaxf((q - a * mean) * (1.f / (NPIX - 1)), 0.f);
        stats[b * 128 + cig * 8 + t] = mean;
        stats[b * 128 + 64 + cig * 8 + t] = sqrtf(var);
    }
}

// ---------- Kernel 2: h=relu(stats@w1+b1); wT[b][co][tap][ci] = bf16(h@w2+b2) ----------
// grid (b=16, chunk=16); j-mapping j = chunk*2304 + tp*256 + t keeps w2/b2 reads coalesced.
__global__ __launch_bounds__(256) void kern_gen(const float* __restrict__ stats,
                                                const float* __restrict__ w1,
                                                const float* __restrict__ b1,
                                                const float* __restrict__ w2,
                                                const float* __restrict__ b2,
                                                short* __restrict__ wT) {
    int b = blockIdx.x, chunk = blockIdx.y;
    __shared__ float st[128];
    __shared__ float h[32];
    int t = threadIdx.x;
    if (t < 128) st[t] = stats[b * 128 + t];
    __syncthreads();
    if (t < 32) {
        float acc = b1[t];
        for (int i = 0; i < 128; i++) acc += st[i] * w1[i * 32 + t];
        h[t] = fmaxf(acc, 0.f);
    }
    __syncthreads();

    int jbase = chunk * 2304;
    float acc[9];
    #pragma unroll
    for (int tp = 0; tp < 9; tp++) acc[tp] = b2[jbase + tp * 256 + t];
    for (int i = 0; i < 32; i++) {
        float hi = h[i];
        const float* w2r = w2 + (size_t)i * KEL + jbase + t;
        #pragma unroll
        for (int tp = 0; tp < 9; tp++) acc[tp] += hi * w2r[tp * 256];
    }
    short* wb = wT + (size_t)b * 64 * 576;
    #pragma unroll
    for (int tp = 0; tp < 9; tp++) {
        int j = jbase + tp * 256 + t;        // original col: j = (co*64+ci)*9 + tap
        int co = j / 576;
        int rem = j - co * 576;
        int ci = rem / 9;
        int tap = rem - ci * 9;
        wb[co * 576 + tap * 64 + ci] = bf16_of(acc[tp]);
    }
}

// ---------- Kernel 3: conv via MFMA ----------
// grid (ytile=32, b=16), 512 thr (8 waves). Block: out rows y0..y0+3, all x, all 64 co.
// Wave w: co-half ch=w&1 (32 co = 2 frags), row r=w>>1. LDS: [6 rows][132 xi][64 ci] bf16,
// 16B-slot XOR swizzle (slot^ = xi&7) -> conflict-free ds_read_b128 B-frags.
__global__ __launch_bounds__(512, 2) void conv_mfma(const short* __restrict__ xT,
                                                    const short* __restrict__ wT,
                                                    float* __restrict__ out) {
    __shared__ short xls[6 * 132 * 64];   // 101376 B

    int ytile = blockIdx.x, b = blockIdx.y;
    int y0 = ytile * 4;
    int t = threadIdx.x;
    int l = t & 63, w = t >> 6;
    int ch = w & 1, r = w >> 1;
    int l15 = l & 15, lg = l >> 4;

    // ---- preload all 18 weight A-frags for both co-16 groups of this wave's half ----
    short8 wf[2][9][2];
    {
        const short* base = wT + ((size_t)(b * 64 + ch * 32 + l15)) * 576 + lg * 8;
        #pragma unroll
        for (int g = 0; g < 2; g++)
            #pragma unroll
            for (int tap = 0; tap < 9; tap++)
                #pragma unroll
                for (int kp = 0; kp < 2; kp++)
                    wf[g][tap][kp] = *(const short8*)(base + g * 16 * 576 + tap * 64 + kp * 32);
    }

    // ---- stage 6 input rows (y0-1 .. y0+4) into swizzled LDS ----
    const short* xTb = xT + ((size_t)b) * NPIX * 64;
    for (int e = t; e < 6 * 1024; e += 512) {
        int lr = e >> 10;
        int c = e & 1023;
        int xcol = c >> 3, slot = c & 7;
        int xi = xcol + 1;
        int y = y0 - 1 + lr;
        short8 v = {0, 0, 0, 0, 0, 0, 0, 0};
        if ((unsigned)y < 128u)
            v = *(const short8*)(xTb + ((size_t)(y * 128 + xcol)) * 64 + slot * 8);
        *(short8*)(xls + (lr * 132 + xi) * 64 + ((slot ^ (xi & 7)) << 3)) = v;
    }
    if (t < 96) {   // x halo columns (x=-1 and x=128) = 0
        int lr = t >> 4, cc = t & 15;
        int xi = (cc & 1) ? 129 : 0;
        int slot = cc >> 1;
        short8 z = {0, 0, 0, 0, 0, 0, 0, 0};
        *(short8*)(xls + (lr * 132 + xi) * 64 + ((slot ^ (xi & 7)) << 3)) = z;
    }
    __syncthreads();

    // ---- compute: 8 N-tiles of 16 px; per tile 9 taps x 2 ksteps x 2 co-frags ----
    float* ob0 = out + ((size_t)(b * 64 + ch * 32 + lg * 4)) * NPIX + (y0 + r) * 128;
    for (int n = 0; n < 8; n++) {
        int x0 = n * 16;
        f32x4 acc0 = {0.f, 0.f, 0.f, 0.f};
        f32x4 acc1 = {0.f, 0.f, 0.f, 0.f};
        #pragma unroll
        for (int tap = 0; tap < 9; tap++) {
            const int dy = tap / 3, dx = tap % 3;
            int lr = r + dy;
            int xi = x0 + l15 + dx;
            const short* rowp = xls + (lr * 132 + xi) * 64;
            int sw = xi & 7;
            #pragma unroll
            for (int kp = 0; kp < 2; kp++) {
                short8 bfrag = *(const short8*)(rowp + (((kp * 4 + lg) ^ sw) << 3));
                acc0 = __builtin_amdgcn_mfma_f32_16x16x32_bf16(wf[0][tap][kp], bfrag, acc0, 0, 0, 0);
                acc1 = __builtin_amdgcn_mfma_f32_16x16x32_bf16(wf[1][tap][kp], bfrag, acc1, 0, 0, 0);
            }
        }
        #pragma unroll
        for (int reg = 0; reg < 4; reg++) {
            ob0[(size_t)reg * NPIX + x0 + l15] = acc0[reg];
            ob0[(size_t)(16 + reg) * NPIX + x0 + l15] = acc1[reg];
        }
    }
}

extern "C" void kernel_launch(void* const* d_in, const int* in_sizes, int n_in,
                              void* d_out, int out_size, void* d_ws, size_t ws_size,
                              hipStream_t stream) {
    const float* x  = (const float*)d_in[0];
    const float* w1 = (const float*)d_in[1];
    const float* b1 = (const float*)d_in[2];
    const float* w2 = (const float*)d_in[3];
    const float* b2 = (const float*)d_in[4];
    float* out = (float*)d_out;

    float* ws_stats = (float*)d_ws;                                   // 2048 f32 = 8 KB
    short* wT = (short*)((char*)d_ws + 8192);                         // 589824 bf16 = 1.18 MB
    short* xT = (short*)((char*)d_ws + 8192 + 1179648);               // 16.8M bf16 = 33.5 MB

    xpose_stats<<<dim3(B_, 8), 256, 0, stream>>>(x, xT, ws_stats);
    kern_gen<<<dim3(B_, 16), 256, 0, stream>>>(ws_stats, w1, b1, w2, b2, wT);
    conv_mfma<<<dim3(32, B_), 512, 0, stream>>>(xT, wT, out);
}

// Round 3
// 80.545 us; speedup vs baseline: 5.8796x; 1.0388x over previous
//
#include <hip/hip_runtime.h>
#include <hip/hip_bf16.h>

// x:[16,64,128,128] f32 -> stats -> MLP -> per-sample kern[64,64,3,3] -> conv(pad=1)
// bf16 MFMA implicit GEMM. xT[b][y][x][ci] bf16, wT[b][co][tap][ci] bf16.
// R3 change: xpose_stats split 16x (row strips) for occupancy; partial stats
// reduced inside kern_gen prologue.

#define B_ 16
#define CI_ 64
#define CO_ 64
#define HW_ 128
#define NPIX 16384
#define KEL 36864

typedef __attribute__((ext_vector_type(4))) float f32x4;
typedef __attribute__((ext_vector_type(8))) short short8;

static __device__ __forceinline__ short bf16_of(float f) {
    __hip_bfloat16 h = __float2bfloat16(f);
    return *reinterpret_cast<short*>(&h);
}

// ---------- Kernel 1: transpose x -> xT bf16 [b][y][x][ci]; partial stats ----------
// grid (b=16, cig=8, part=16): block = 8 ci x 8 rows (1024 px). part[b][cig][p][16]
// holds 8x{sum,sumsq}. 2048 blocks -> ~32 waves/CU (R2 version had 128 blocks, 4% occ).
__global__ __launch_bounds__(256) void xpose_stats(const float* __restrict__ x,
                                                   short* __restrict__ xT,
                                                   float* __restrict__ part) {
    int b = blockIdx.x, cig = blockIdx.y, pt = blockIdx.z;
    int t = threadIdx.x;
    int y = pt * 8 + (t >> 5);
    int x0 = (t & 31) * 4;

    const float* xb = x + ((size_t)(b * 64 + cig * 8)) * NPIX;
    short* xTb = xT + ((size_t)b * NPIX) * 64 + cig * 8;

    float s[8], ss[8];
    f32x4 v[8];
    #pragma unroll
    for (int c = 0; c < 8; c++) {
        v[c] = *(const f32x4*)(xb + (size_t)c * NPIX + y * 128 + x0);
        s[c]  = v[c][0] + v[c][1] + v[c][2] + v[c][3];
        ss[c] = v[c][0]*v[c][0] + v[c][1]*v[c][1] + v[c][2]*v[c][2] + v[c][3]*v[c][3];
    }
    #pragma unroll
    for (int xi = 0; xi < 4; xi++) {
        short8 o;
        #pragma unroll
        for (int c = 0; c < 8; c++) o[c] = bf16_of(v[c][xi]);
        *(short8*)(xTb + ((size_t)(y * 128 + x0 + xi)) * 64) = o;
    }

    __shared__ float red[4][16];
    int lane = t & 63, w = t >> 6;
    #pragma unroll
    for (int c = 0; c < 8; c++) {
        float a = s[c], q = ss[c];
        for (int off = 32; off; off >>= 1) { a += __shfl_down(a, off); q += __shfl_down(q, off); }
        if (lane == 0) { red[w][c * 2] = a; red[w][c * 2 + 1] = q; }
    }
    __syncthreads();
    if (t < 16)
        part[((size_t)((b * 8 + cig) * 16 + pt)) * 16 + t] =
            red[0][t] + red[1][t] + red[2][t] + red[3][t];
}

// ---------- Kernel 2: reduce partials -> stats; h=relu(stats@w1+b1); wT = bf16(h@w2+b2) ----------
__global__ __launch_bounds__(256) void kern_gen(const float* __restrict__ part,
                                                const float* __restrict__ w1,
                                                const float* __restrict__ b1,
                                                const float* __restrict__ w2,
                                                const float* __restrict__ b2,
                                                short* __restrict__ wT) {
    int b = blockIdx.x, chunk = blockIdx.y;
    __shared__ float st[128];
    __shared__ float h[32];
    int t = threadIdx.x;
    if (t < 64) {                       // per-ci reduction of 16 partials
        int cig = t >> 3, cl = t & 7;
        const float* pb = part + ((size_t)(b * 8 + cig) * 16) * 16 + cl * 2;
        float s = 0.f, q = 0.f;
        #pragma unroll
        for (int p = 0; p < 16; p++) { s += pb[p * 16]; q += pb[p * 16 + 1]; }
        float mean = s * (1.f / NPIX);
        float var = fmaxf((q - s * mean) * (1.f / (NPIX - 1)), 0.f);
        st[t] = mean;
        st[64 + t] = sqrtf(var);
    }
    __syncthreads();
    if (t < 32) {
        float acc = b1[t];
        for (int i = 0; i < 128; i++) acc += st[i] * w1[i * 32 + t];
        h[t] = fmaxf(acc, 0.f);
    }
    __syncthreads();

    int jbase = chunk * 2304;
    float acc[9];
    #pragma unroll
    for (int tp = 0; tp < 9; tp++) acc[tp] = b2[jbase + tp * 256 + t];
    for (int i = 0; i < 32; i++) {
        float hi = h[i];
        const float* w2r = w2 + (size_t)i * KEL + jbase + t;
        #pragma unroll
        for (int tp = 0; tp < 9; tp++) acc[tp] += hi * w2r[tp * 256];
    }
    short* wb = wT + (size_t)b * 64 * 576;
    #pragma unroll
    for (int tp = 0; tp < 9; tp++) {
        int j = jbase + tp * 256 + t;        // original col: j = (co*64+ci)*9 + tap
        int co = j / 576;
        int rem = j - co * 576;
        int ci = rem / 9;
        int tap = rem - ci * 9;
        wb[co * 576 + tap * 64 + ci] = bf16_of(acc[tp]);
    }
}

// ---------- Kernel 3: conv via MFMA (unchanged from R2) ----------
__global__ __launch_bounds__(512, 2) void conv_mfma(const short* __restrict__ xT,
                                                    const short* __restrict__ wT,
                                                    float* __restrict__ out) {
    __shared__ short xls[6 * 132 * 64];   // 101376 B

    int ytile = blockIdx.x, b = blockIdx.y;
    int y0 = ytile * 4;
    int t = threadIdx.x;
    int l = t & 63, w = t >> 6;
    int ch = w & 1, r = w >> 1;
    int l15 = l & 15, lg = l >> 4;

    short8 wf[2][9][2];
    {
        const short* base = wT + ((size_t)(b * 64 + ch * 32 + l15)) * 576 + lg * 8;
        #pragma unroll
        for (int g = 0; g < 2; g++)
            #pragma unroll
            for (int tap = 0; tap < 9; tap++)
                #pragma unroll
                for (int kp = 0; kp < 2; kp++)
                    wf[g][tap][kp] = *(const short8*)(base + g * 16 * 576 + tap * 64 + kp * 32);
    }

    const short* xTb = xT + ((size_t)b) * NPIX * 64;
    for (int e = t; e < 6 * 1024; e += 512) {
        int lr = e >> 10;
        int c = e & 1023;
        int xcol = c >> 3, slot = c & 7;
        int xi = xcol + 1;
        int y = y0 - 1 + lr;
        short8 v = {0, 0, 0, 0, 0, 0, 0, 0};
        if ((unsigned)y < 128u)
            v = *(const short8*)(xTb + ((size_t)(y * 128 + xcol)) * 64 + slot * 8);
        *(short8*)(xls + (lr * 132 + xi) * 64 + ((slot ^ (xi & 7)) << 3)) = v;
    }
    if (t < 96) {
        int lr = t >> 4, cc = t & 15;
        int xi = (cc & 1) ? 129 : 0;
        int slot = cc >> 1;
        short8 z = {0, 0, 0, 0, 0, 0, 0, 0};
        *(short8*)(xls + (lr * 132 + xi) * 64 + ((slot ^ (xi & 7)) << 3)) = z;
    }
    __syncthreads();

    float* ob0 = out + ((size_t)(b * 64 + ch * 32 + lg * 4)) * NPIX + (y0 + r) * 128;
    for (int n = 0; n < 8; n++) {
        int x0 = n * 16;
        f32x4 acc0 = {0.f, 0.f, 0.f, 0.f};
        f32x4 acc1 = {0.f, 0.f, 0.f, 0.f};
        #pragma unroll
        for (int tap = 0; tap < 9; tap++) {
            const int dy = tap / 3, dx = tap % 3;
            int lr = r + dy;
            int xi = x0 + l15 + dx;
            const short* rowp = xls + (lr * 132 + xi) * 64;
            int sw = xi & 7;
            #pragma unroll
            for (int kp = 0; kp < 2; kp++) {
                short8 bfrag = *(const short8*)(rowp + (((kp * 4 + lg) ^ sw) << 3));
                acc0 = __builtin_amdgcn_mfma_f32_16x16x32_bf16(wf[0][tap][kp], bfrag, acc0, 0, 0, 0);
                acc1 = __builtin_amdgcn_mfma_f32_16x16x32_bf16(wf[1][tap][kp], bfrag, acc1, 0, 0, 0);
            }
        }
        #pragma unroll
        for (int reg = 0; reg < 4; reg++) {
            ob0[(size_t)reg * NPIX + x0 + l15] = acc0[reg];
            ob0[(size_t)(16 + reg) * NPIX + x0 + l15] = acc1[reg];
        }
    }
}

extern "C" void kernel_launch(void* const* d_in, const int* in_sizes, int n_in,
                              void* d_out, int out_size, void* d_ws, size_t ws_size,
                              hipStream_t stream) {
    const float* x  = (const float*)d_in[0];
    const float* w1 = (const float*)d_in[1];
    const float* b1 = (const float*)d_in[2];
    const float* w2 = (const float*)d_in[3];
    const float* b2 = (const float*)d_in[4];
    float* out = (float*)d_out;

    float* part = (float*)d_ws;                                        // 16*8*16*16 f32 = 128 KB
    short* wT = (short*)((char*)d_ws + 131072);                        // 1.18 MB
    short* xT = (short*)((char*)d_ws + 131072 + 1179648);              // 33.5 MB

    xpose_stats<<<dim3(B_, 8, 16), 256, 0, stream>>>(x, xT, part);
    kern_gen<<<dim3(B_, 16), 256, 0, stream>>>(part, w1, b1, w2, b2, wT);
    conv_mfma<<<dim3(32, B_), 512, 0, stream>>>(xT, wT, out);
}